// Round 8
// baseline (127.344 us; speedup 1.0000x reference)
//
#include <hip/hip_runtime.h>
#include <hip/hip_bf16.h>

// Problem constants (from reference)
constexpr int C   = 4096;   // HIDDEN_DIM
constexpr int NE  = 4;      // EXPANSION
constexpr int B   = 4096;   // batch rows
constexpr int THREADS = 512;
constexpr int PER = C / THREADS;  // 8 columns per thread
constexpr float EPSV = 1e-5f;

typedef float vfloat4 __attribute__((ext_vector_type(4)));  // clang-native, NT-store legal

// Manual RNE round-to-bf16-and-back (value-based)
__device__ inline float bf16_rne(float f) {
    unsigned int u = __float_as_uint(f);
    unsigned int r = (u + 0x7FFFu + ((u >> 16) & 1u)) & 0xFFFF0000u;
    return __uint_as_float(r);
}

// Single fused kernel: one block per row. Sinkhorn runs lane-parallel on wave 0,
// hidden under the x-load latency.
__global__ __launch_bounds__(THREADS)
void mhc_fused(const float* __restrict__ x,
               const float* __restrict__ w,   // rmsnorm_weight stored as f32 on device
               const float* __restrict__ Hpre,
               const float* __restrict__ Hpost,
               const float* __restrict__ Hres,
               float* __restrict__ out) {
    const int b   = blockIdx.x;
    const int tid = threadIdx.x;
    const size_t rowbase = (size_t)b * NE * C;
    const int c0 = tid * PER;

    // ---- x: 4 streams x 8 cols, float4 vectorized, read ONCE ----
    float xs[NE][PER];
    #pragma unroll
    for (int k = 0; k < NE; ++k) {
        const float4* p = reinterpret_cast<const float4*>(x + rowbase + (size_t)k * C + c0);
        float4 a = p[0];
        float4 bq = p[1];
        xs[k][0] = a.x;  xs[k][1] = a.y;  xs[k][2] = a.z;  xs[k][3] = a.w;
        xs[k][4] = bq.x; xs[k][5] = bq.y; xs[k][6] = bq.z; xs[k][7] = bq.w;
    }

    __shared__ float sM[NE * NE];
    __shared__ float red[THREADS / 64];

    // ---- wave 0: lane-parallel Sinkhorn (butterfly), overlapped with x loads ----
    // lane l<16 holds M[i][j], i=l>>2, j=l&3. Row sums: xor 1,2. Col sums: xor 4,8.
    if (tid < 64) {
        float m = (tid < 16) ? expf(Hres[tid]) : 0.0f;
        for (int it = 0; it < 20; ++it) {
            float r = m + __shfl_xor(m, 1);
            r += __shfl_xor(r, 2);
            m /= fmaxf(r, EPSV);
            float cs = m + __shfl_xor(m, 4);
            cs += __shfl_xor(cs, 8);
            m /= fmaxf(cs, EPSV);
        }
        if (tid < 16) sM[tid] = m;
    }

    // ---- gates (uniform, cheap, per-thread) ----
    const float s0 = 1.0f / (1.0f + expf(-Hpre[0]));
    const float s1 = 1.0f / (1.0f + expf(-Hpre[1]));
    const float s2 = 1.0f / (1.0f + expf(-Hpre[2]));
    const float s3 = 1.0f / (1.0f + expf(-Hpre[3]));
    float hp[NE];
    #pragma unroll
    for (int i = 0; i < NE; ++i) hp[i] = 2.0f / (1.0f + expf(-Hpost[i]));

    // ---- aggregate + bf16 RNE round + sum of squares ----
    float aggbf[PER];
    float ss = 0.0f;
    #pragma unroll
    for (int c = 0; c < PER; ++c) {
        float a = s0 * xs[0][c] + s1 * xs[1][c] + s2 * xs[2][c] + s3 * xs[3][c];
        float abf = bf16_rne(a);
        aggbf[c] = abf;
        ss += abf * abf;
    }

    // ---- block reduction (wave64 butterfly, then LDS across 8 waves) ----
    #pragma unroll
    for (int off = 32; off > 0; off >>= 1) ss += __shfl_xor(ss, off);
    const int lane = tid & 63;
    const int wid  = tid >> 6;
    if (lane == 0) red[wid] = ss;
    __syncthreads();   // also publishes sM
    float tot = 0.0f;
    #pragma unroll
    for (int i = 0; i < THREADS / 64; ++i) tot += red[i];

    const float rinv = 1.0f / sqrtf(tot * (1.0f / (float)C) + EPSV);

    // ---- y = aggbf * rinv * w  (w is f32 on device; float4 loads, L2/L3-resident) ----
    float y[PER];
    {
        const float4* pw = reinterpret_cast<const float4*>(w + c0);
        float4 w0 = pw[0];
        float4 w1 = pw[1];
        y[0] = aggbf[0] * rinv * w0.x;  y[1] = aggbf[1] * rinv * w0.y;
        y[2] = aggbf[2] * rinv * w0.z;  y[3] = aggbf[3] * rinv * w0.w;
        y[4] = aggbf[4] * rinv * w1.x;  y[5] = aggbf[5] * rinv * w1.y;
        y[6] = aggbf[6] * rinv * w1.z;  y[7] = aggbf[7] * rinv * w1.w;
    }

    // ---- Sinkhorn matrix from LDS (uniform broadcast) ----
    float M[NE][NE];
    #pragma unroll
    for (int i = 0; i < NE; ++i)
        #pragma unroll
        for (int j = 0; j < NE; ++j)
            M[i][j] = sM[i * NE + j];

    // ---- outputs: NONTEMPORAL stores (out is never re-read; keep x in L3) ----
    #pragma unroll
    for (int i = 0; i < NE; ++i) {
        float o[PER];
        #pragma unroll
        for (int c = 0; c < PER; ++c) {
            o[c] = M[i][0] * xs[0][c] + M[i][1] * xs[1][c]
                 + M[i][2] * xs[2][c] + M[i][3] * xs[3][c]
                 + hp[i] * y[c];
        }
        vfloat4* po = reinterpret_cast<vfloat4*>(out + rowbase + (size_t)i * C + c0);
        vfloat4 v0 = { o[0], o[1], o[2], o[3] };
        vfloat4 v1 = { o[4], o[5], o[6], o[7] };
        __builtin_nontemporal_store(v0, po);
        __builtin_nontemporal_store(v1, po + 1);
    }
}

extern "C" void kernel_launch(void* const* d_in, const int* in_sizes, int n_in,
                              void* d_out, int out_size, void* d_ws, size_t ws_size,
                              hipStream_t stream) {
    const float* x     = (const float*)d_in[0];
    const float* w     = (const float*)d_in[1];   // f32 on device (np has no bf16)
    const float* Hpre  = (const float*)d_in[2];
    const float* Hpost = (const float*)d_in[3];
    const float* Hres  = (const float*)d_in[4];
    float* out         = (float*)d_out;

    mhc_fused<<<B, THREADS, 0, stream>>>(x, w, Hpre, Hpost, Hres, out);
}

// Round 9
// 113.201 us; speedup vs baseline: 1.1249x; 1.1249x over previous
//
#include <hip/hip_runtime.h>
#include <hip/hip_bf16.h>

// Problem constants (from reference)
constexpr int C   = 4096;   // HIDDEN_DIM
constexpr int NE  = 4;      // EXPANSION
constexpr int B   = 4096;   // batch rows
constexpr int THREADS = 512;
constexpr int PER = C / THREADS;  // 8 columns per thread
constexpr float EPSV = 1e-5f;

// Manual RNE round-to-bf16-and-back (value-based)
__device__ inline float bf16_rne(float f) {
    unsigned int u = __float_as_uint(f);
    unsigned int r = (u + 0x7FFFu + ((u >> 16) & 1u)) & 0xFFFF0000u;
    return __uint_as_float(r);
}

// Single fused kernel: one block per row. Sinkhorn runs lane-parallel on wave 0,
// hidden under the x-load latency. Normal write-back stores (NT stores measured
// +38% HBM write traffic in round 8 — reverted).
__global__ __launch_bounds__(THREADS)
void mhc_fused(const float* __restrict__ x,
               const float* __restrict__ w,   // rmsnorm_weight stored as f32 on device
               const float* __restrict__ Hpre,
               const float* __restrict__ Hpost,
               const float* __restrict__ Hres,
               float* __restrict__ out) {
    const int b   = blockIdx.x;
    const int tid = threadIdx.x;
    const size_t rowbase = (size_t)b * NE * C;
    const int c0 = tid * PER;

    // ---- x: 4 streams x 8 cols, float4 vectorized, read ONCE ----
    float xs[NE][PER];
    #pragma unroll
    for (int k = 0; k < NE; ++k) {
        const float4* p = reinterpret_cast<const float4*>(x + rowbase + (size_t)k * C + c0);
        float4 a = p[0];
        float4 bq = p[1];
        xs[k][0] = a.x;  xs[k][1] = a.y;  xs[k][2] = a.z;  xs[k][3] = a.w;
        xs[k][4] = bq.x; xs[k][5] = bq.y; xs[k][6] = bq.z; xs[k][7] = bq.w;
    }

    __shared__ float sM[NE * NE];
    __shared__ float red[THREADS / 64];

    // ---- wave 0: lane-parallel Sinkhorn (butterfly), overlapped with x loads ----
    // lane l<16 holds M[i][j], i=l>>2, j=l&3. Row sums: xor 1,2. Col sums: xor 4,8.
    if (tid < 64) {
        float m = (tid < 16) ? expf(Hres[tid]) : 0.0f;
        for (int it = 0; it < 20; ++it) {
            float r = m + __shfl_xor(m, 1);
            r += __shfl_xor(r, 2);
            m /= fmaxf(r, EPSV);
            float cs = m + __shfl_xor(m, 4);
            cs += __shfl_xor(cs, 8);
            m /= fmaxf(cs, EPSV);
        }
        if (tid < 16) sM[tid] = m;
    }

    // ---- gates (uniform, cheap, per-thread) ----
    const float s0 = 1.0f / (1.0f + expf(-Hpre[0]));
    const float s1 = 1.0f / (1.0f + expf(-Hpre[1]));
    const float s2 = 1.0f / (1.0f + expf(-Hpre[2]));
    const float s3 = 1.0f / (1.0f + expf(-Hpre[3]));
    float hp[NE];
    #pragma unroll
    for (int i = 0; i < NE; ++i) hp[i] = 2.0f / (1.0f + expf(-Hpost[i]));

    // ---- aggregate + bf16 RNE round + sum of squares ----
    float aggbf[PER];
    float ss = 0.0f;
    #pragma unroll
    for (int c = 0; c < PER; ++c) {
        float a = s0 * xs[0][c] + s1 * xs[1][c] + s2 * xs[2][c] + s3 * xs[3][c];
        float abf = bf16_rne(a);
        aggbf[c] = abf;
        ss += abf * abf;
    }

    // ---- block reduction (wave64 butterfly, then LDS across 8 waves) ----
    #pragma unroll
    for (int off = 32; off > 0; off >>= 1) ss += __shfl_xor(ss, off);
    const int lane = tid & 63;
    const int wid  = tid >> 6;
    if (lane == 0) red[wid] = ss;
    __syncthreads();   // also publishes sM
    float tot = 0.0f;
    #pragma unroll
    for (int i = 0; i < THREADS / 64; ++i) tot += red[i];

    const float rinv = 1.0f / sqrtf(tot * (1.0f / (float)C) + EPSV);

    // ---- y = aggbf * rinv * w  (w is f32 on device; float4 loads, L2/L3-resident) ----
    float y[PER];
    {
        const float4* pw = reinterpret_cast<const float4*>(w + c0);
        float4 w0 = pw[0];
        float4 w1 = pw[1];
        y[0] = aggbf[0] * rinv * w0.x;  y[1] = aggbf[1] * rinv * w0.y;
        y[2] = aggbf[2] * rinv * w0.z;  y[3] = aggbf[3] * rinv * w0.w;
        y[4] = aggbf[4] * rinv * w1.x;  y[5] = aggbf[5] * rinv * w1.y;
        y[6] = aggbf[6] * rinv * w1.z;  y[7] = aggbf[7] * rinv * w1.w;
    }

    // ---- Sinkhorn matrix from LDS (uniform broadcast) ----
    float M[NE][NE];
    #pragma unroll
    for (int i = 0; i < NE; ++i)
        #pragma unroll
        for (int j = 0; j < NE; ++j)
            M[i][j] = sM[i * NE + j];

    // ---- outputs: out[b,i,c] = sum_j M[i][j]*x[b,j,c] + hp[i]*y[c] ----
    #pragma unroll
    for (int i = 0; i < NE; ++i) {
        float o[PER];
        #pragma unroll
        for (int c = 0; c < PER; ++c) {
            o[c] = M[i][0] * xs[0][c] + M[i][1] * xs[1][c]
                 + M[i][2] * xs[2][c] + M[i][3] * xs[3][c]
                 + hp[i] * y[c];
        }
        float4* po = reinterpret_cast<float4*>(out + rowbase + (size_t)i * C + c0);
        po[0] = make_float4(o[0], o[1], o[2], o[3]);
        po[1] = make_float4(o[4], o[5], o[6], o[7]);
    }
}

extern "C" void kernel_launch(void* const* d_in, const int* in_sizes, int n_in,
                              void* d_out, int out_size, void* d_ws, size_t ws_size,
                              hipStream_t stream) {
    const float* x     = (const float*)d_in[0];
    const float* w     = (const float*)d_in[1];   // f32 on device (np has no bf16)
    const float* Hpre  = (const float*)d_in[2];
    const float* Hpost = (const float*)d_in[3];
    const float* Hres  = (const float*)d_in[4];
    float* out         = (float*)d_out;

    mhc_fused<<<B, THREADS, 0, stream>>>(x, w, Hpre, Hpost, Hres, out);
}